// Round 8
// baseline (173.390 us; speedup 1.0000x reference)
//
#include <hip/hip_runtime.h>
#include <hip/hip_bf16.h>
#include <math.h>

#define NN 128
#define TRI 8256          // 128*129/2
#define BATCH 2048
#define M_L 10
#define KAPPA 0.276f

using half8  = __attribute__((ext_vector_type(8))) _Float16;  // MFMA A/B frag (4 VGPRs)
using half2v = __attribute__((ext_vector_type(2))) _Float16;
using f32x4  = __attribute__((ext_vector_type(4))) float;     // MFMA C/D frag

// ---------------------------------------------------------------------------
// fp64 Sturm sign count reading T directly from LDS ab_s (broadcast reads,
// minimal registers -- R15 tail form, kept).
// ---------------------------------------------------------------------------
__device__ inline int sturm_lds(const float* __restrict__ ab_s, double x) {
    double pm = 1.0;
    double p  = (double)ab_s[0] - x;
    int c = (p < 0.0);
    #pragma unroll
    for (int i = 1; i < M_L; i++) {
        double bb = (double)ab_s[10 + i - 1];
        double pn = ((double)ab_s[i] - x) * p - (bb * bb) * pm;
        c += ((pn < 0.0) != (p < 0.0));
        pm = p; p = pn;
    }
    return c;
}

// ---------------------------------------------------------------------------
// Kernel 1: per-batch fused Lanczos + eig tail.  R16: 512 THREADS / 8 WAVES.
// R14/R15 lesson (quantified): pool = 512 regs/wave-slot/SIMD, unified
// VGPR+AGPR. A 4-wave design carries acc[2][8]=64 AGPR -> 120 total -> 4
// waves/SIMD forever. Splitting the GEMM one-band-per-wave (8 waves) halves
// the accumulator to acc[8]=32 AGPR -> ~77 total -> 6 waves/SIMD = 3 blocks
// x 8 waves = 24 waves/CU (1.5x R13). __launch_bounds__(512,6) caps at 85.
// M never materialized (R15): matvec runs from AGPRs; wave w owns M cols
// [16w,16w+16): zj = sum_q acc[j][q]*y[16w+4g+q], shfl_xor(16,32) over g,
// lanes<16 write part slice w; hub sums 8 slices. No writeback, no hoist,
// M stays fp32. LDS = exactly 32768 (ysf/part/ab_s alias dead L buffer).
// R12/R13 tail: lane-split Sturm (wave b&7), branchless brackets.
// R14 kept: XOR-swizzled [128][128] L, branchless stage scatter.
// ---------------------------------------------------------------------------
__global__ __launch_bounds__(512, 6) void lanczos_kernel(
    const float* __restrict__ net_out,
    const float* __restrict__ U1,
    const float* __restrict__ v_in,
    float* __restrict__ contrib)   // [BATCH]
{
    __shared__ __align__(16) _Float16 Msh[128 * 128];   // 32768 B exactly (L, swizzled)
    // aliases into Msh, valid only AFTER the post-GEMM barrier (L dead):
    float* ysf  = (float*)Msh;             // 128 f32   (bytes    0..511)
    float* part = (float*)(Msh + 256);     // 1024 f32  (bytes  512..4607), 8 slices
    float* ab_s = (float*)(Msh + 2304);    // 20 f32    (bytes 4608..4687)

    const int b = blockIdx.x;
    const int t = threadIdx.x;
    const int lane = t & 63;
    const int w = t >> 6;       // wave id 0..7

    // ---- issue wave-0 global loads EARLY (latency hides under staging) ----
    float2 vv = {0.f, 0.f}, uu = {0.f, 0.f};
    if (w == 0) {
        vv = *(const float2*)(v_in + (size_t)b * NN + 2 * lane);
        uu = *(const float2*)(U1 + (size_t)b * 128 + 2 * lane);
    }

    // ---- zero Msh (upper triangle must be 0; swizzle is zero-invariant) ----
    {
        unsigned long long* z = (unsigned long long*)Msh;
        #pragma unroll
        for (int k = t; k < 128 * 128 / 4; k += 512) z[k] = 0ULL;
    }
    __syncthreads();

    // ---- stage L: coalesced float4 reads of packed tril, swizzled scatter ----
    // r = floor((sqrt(8e+1)-1)/2) exact for e<=8255 (R13 proof).
    {
        const float4* src4 = (const float4*)(net_out + (size_t)b * TRI);
        for (int q = t; q < TRI / 4; q += 512) {
            float4 f = src4[q];
            const int e = 4 * q;
            float vals[4] = {f.x, f.y, f.z, f.w};
            #pragma unroll
            for (int i = 0; i < 4; i++) {
                int ei = e + i;
                int r = (int)((sqrtf((float)(8 * ei) + 1.0f) - 1.0f) * 0.5f);
                int c = ei - ((r * (r + 1)) >> 1);
                Msh[r * 128 + (c ^ ((r & 7) << 3))] = (_Float16)vals[i];
            }
        }
    }
    __syncthreads();

    // ---- GEMM: band w of M = L * L^T into acc (no writeback; 32 AGPR) ----
    // row (16*j+m) & 7 == m & 7, so the swizzle term is ((m&7)<<3) throughout.
    const int m = lane & 15;
    const int g = lane >> 4;
    f32x4 acc[8];
    {
        const int sw = (m & 7) << 3;
        #pragma unroll
        for (int j = 0; j < 8; j++) acc[j] = (f32x4){0.f, 0.f, 0.f, 0.f};
        #pragma unroll
        for (int kc = 0; kc < 4; kc++) {
            const int col = (kc * 32 + g * 8) ^ sw;   // 8-half run stays contiguous
            half8 a0 = *(const half8*)&Msh[(16 * w + m) * 128 + col];
            #pragma unroll
            for (int j = 0; j < 8; j++) {
                half8 bfr = *(const half8*)&Msh[(16 * j + m) * 128 + col];
                acc[j] = __builtin_amdgcn_mfma_f32_16x16x32_f16(a0, bfr, acc[j], 0, 0, 0);
            }
        }
    }
    __syncthreads();   // ALL L reads complete -> ysf/part/ab_s may alias Msh

    // ---- wave-0 state init: x (2 elems/lane), gauge regs, first y ----
    float x0 = 0.f, x1 = 0.f, p0 = 0.f, p1 = 0.f, beta = 0.f;
    float u0c = 0.f, u1c = 0.f, u0m = 0.f, u1m = 0.f;
    const int l_ip = (lane + 8) & 63;                  // site (i+1, j)
    const int l_jp = (lane & 56) | ((lane + 1) & 7);   // site (i, j+1)
    const int l_im = (lane + 56) & 63;                 // site (i-1, j)
    const int l_jm = (lane & 56) | ((lane + 7) & 7);   // site (i, j-1)

    if (w == 0) {
        float s = vv.x * vv.x + vv.y * vv.y;
        #pragma unroll
        for (int o = 1; o < 64; o <<= 1) s += __shfl_xor(s, o, 64);
        float inv = 1.0f / sqrtf(s);
        x0 = vv.x * inv; x1 = vv.y * inv;
        u0c = uu.x; u1c = uu.y;
        u0m = __shfl(u0c, l_im, 64);   // u0 at (i-1, j)
        u1m = __shfl(u1c, l_jm, 64);   // u1 at (i, j-1)

        // first y = dd(x), stored as f32
        float a0 = __shfl(x0, l_ip, 64), a1 = __shfl(x1, l_ip, 64);
        float b0 = __shfl(x0, l_jp, 64), b1 = __shfl(x1, l_jp, 64);
        float c0 = __shfl(x0, l_im, 64), c1 = __shfl(x1, l_im, 64);
        float d0 = __shfl(x0, l_jm, 64), d1 = __shfl(x1, l_jm, 64);
        float y0 = x0 - KAPPA * (u0c * a0 + u1c * b0 + u0m * c0 + u1m * d0);
        float y1 = x1 - KAPPA * (u0c * a1 + u1c * b1 + u0m * c1 + u1m * d1);
        *(float2*)&ysf[2 * lane] = (float2){y0, y1};
    }
    __syncthreads();   // ysf ready

    // =================== loop: 2 barriers per iteration ===================
    for (int it = 0; it < M_L; it++) {
        // ---- all 8 waves: matvec from AGPR-resident M (band w) ----
        {
            float4 yb = *(const float4*)&ysf[16 * w + 4 * g];   // broadcast per g
            #pragma unroll
            for (int j = 0; j < 8; j++) {
                f32x4 A = acc[j];
                float zj = A[0] * yb.x + A[1] * yb.y + A[2] * yb.z + A[3] * yb.w;
                zj += __shfl_xor(zj, 16, 64);   // combine g pairs
                zj += __shfl_xor(zj, 32, 64);   // full g reduction
                if (lane < 16) part[w * 128 + 16 * j + lane] = zj;
            }
        }
        __syncthreads();   // B1: part ready

        // ---- wave 0: combine 8 slices, reduce, update, dd, broadcast y ----
        if (w == 0) {
            float z0 = 0.f, z1 = 0.f;
            #pragma unroll
            for (int ww = 0; ww < 8; ww++) {
                float2 pw = *(const float2*)&part[ww * 128 + 2 * lane];
                z0 += pw.x; z1 += pw.y;
            }

            float s1 = z0 * x0 + z1 * x1;
            float s2 = z0 * z0 + z1 * z1;
            float s3 = z0 * p0 + z1 * p1;
            #pragma unroll
            for (int o = 1; o < 64; o <<= 1) {
                s1 += __shfl_xor(s1, o, 64);
                s2 += __shfl_xor(s2, o, 64);
                s3 += __shfl_xor(s3, o, 64);
            }
            float alpha = s1;
            float b2 = s2 - alpha * alpha - beta * (2.0f * s3 - beta);
            float bn = sqrtf(fmaxf(b2, 0.0f));
            float w0 = z0 - alpha * x0 - beta * p0;
            float w1 = z1 - alpha * x1 - beta * p1;
            float inv = 1.0f / (bn + 1e-30f);
            p0 = x0; p1 = x1;
            x0 = w0 * inv; x1 = w1 * inv;
            beta = bn;
            if (lane == 0) {
                ab_s[it]      = alpha;
                ab_s[10 + it] = bn;
            }

            // dd for next iteration
            float a0 = __shfl(x0, l_ip, 64), a1 = __shfl(x1, l_ip, 64);
            float b0 = __shfl(x0, l_jp, 64), b1 = __shfl(x1, l_jp, 64);
            float c0 = __shfl(x0, l_im, 64), c1 = __shfl(x1, l_im, 64);
            float d0 = __shfl(x0, l_jm, 64), d1 = __shfl(x1, l_jm, 64);
            float y0 = x0 - KAPPA * (u0c * a0 + u1c * b0 + u0m * c0 + u1m * d0);
            float y1 = x1 - KAPPA * (u0c * a1 + u1c * b1 + u0m * c1 + u1m * d1);
            *(float2*)&ysf[2 * lane] = (float2){y0, y1};
        }
        __syncthreads();   // B2: ysf ready for next matvec; also makes ab_s
                           //     visible to ALL waves after the last iter
    }

    // ============ eig tail: ONE wave (b&7), lane-split Sturm ============
    if (w != (b & 7)) return;   // no barriers below this point

    // Gershgorin bounds straight from LDS (broadcast reads, minimal regs)
    double glo = 1e300, ghi = -1e300;
    #pragma unroll
    for (int i = 0; i < M_L; i++) {
        double ai = (double)ab_s[i];
        double rr = 0.0;
        if (i > 0)        rr += fabs((double)ab_s[10 + i - 1]);
        if (i < M_L - 1)  rr += fabs((double)ab_s[10 + i]);
        glo = fmin(glo, ai - rr);
        ghi = fmax(ghi, ai + rr);
    }

    const int kk = lane & 31;
    const bool topHalf = (lane >= 32);

    // Phase 1: lanes 0-31 find lmax (K=10), lanes 32-63 find lmin (K=1);
    // 33-section x 4 rounds; branchless bracket update.
    const int K = topHalf ? 1 : M_L;
    double lo = glo, hi = ghi;
    for (int round = 0; round < 4; round++) {
        double wdt = (hi - lo) * (1.0 / 33.0);
        double x = lo + wdt * (double)(kk + 1);
        int cnt = sturm_lds(ab_s, x);
        unsigned long long m64 = __ballot(cnt >= K);
        unsigned mm = topHalf ? (unsigned)(m64 >> 32)
                              : (unsigned)(m64 & 0xffffffffu);
        int p = (mm == 0u) ? 32 : (__ffs(mm) - 1);
        double nlo = lo + wdt * (double)p;
        hi = (mm == 0u) ? hi : (lo + wdt * (double)(p + 1));
        lo = nlo;
    }
    double mid = 0.5 * (lo + hi);
    double lmax = __shfl(mid, 0, 64);
    double lmin = __shfl(mid, 32, 64);
    double maxabs = fmax(fabs(lmax), fabs(lmin));

    // Phase 2: window |lambda|min -- lanes 0-31 eval +s, lanes 32-63 eval -s;
    // combine via shfl_xor(32); 33-section x 4 rounds; branchless update.
    double wlo = 0.0, whi = maxabs;
    for (int round = 0; round < 4; round++) {
        double wdt = (whi - wlo) * (1.0 / 33.0);
        double s = wlo + wdt * (double)(kk + 1);
        double x = topHalf ? -s : s;
        int cnt = sturm_lds(ab_s, x);
        int o = __shfl_xor(cnt, 32, 64);
        int inwin = topHalf ? (o - cnt) : (cnt - o);
        unsigned long long m64 = __ballot(inwin >= 1);
        unsigned mm = (unsigned)(m64 & 0xffffffffu);   // halves mirror
        int p = (mm == 0u) ? 32 : (__ffs(mm) - 1);
        double nlo = wlo + wdt * (double)p;
        whi = (mm == 0u) ? whi : (wlo + wdt * (double)(p + 1));
        wlo = nlo;
    }
    double minabs = 0.5 * (wlo + whi);
    if (lane == 0) contrib[b] = (float)(maxabs * maxabs - minabs * minabs);
}

// ---------------------------------------------------------------------------
// Kernel 2: reduce 2048 contributions -> d_out[0] (mean)
// ---------------------------------------------------------------------------
__global__ __launch_bounds__(1024) void reduce_kernel(
    const float* __restrict__ contrib, float* __restrict__ out)
{
    __shared__ float red[16];
    int t = threadIdx.x;
    float s = contrib[t] + contrib[t + 1024];
    #pragma unroll
    for (int o = 32; o > 0; o >>= 1) s += __shfl_down(s, o, 64);
    if ((t & 63) == 0) red[t >> 6] = s;
    __syncthreads();
    if (t < 64) {
        float r = (t < 16) ? red[t] : 0.0f;
        #pragma unroll
        for (int o = 8; o > 0; o >>= 1) r += __shfl_down(r, o, 64);
        if (t == 0) out[0] = r / (float)BATCH;
    }
}

extern "C" void kernel_launch(void* const* d_in, const int* in_sizes, int n_in,
                              void* d_out, int out_size, void* d_ws, size_t ws_size,
                              hipStream_t stream) {
    const float* net_out = (const float*)d_in[0];
    const float* U1      = (const float*)d_in[1];
    const float* v       = (const float*)d_in[2];
    float* contrib = (float*)d_ws;   // BATCH floats

    lanczos_kernel<<<BATCH, 512, 0, stream>>>(net_out, U1, v, contrib);
    reduce_kernel<<<1, 1024, 0, stream>>>(contrib, (float*)d_out);
}

// Round 9
// 139.114 us; speedup vs baseline: 1.2464x; 1.2464x over previous
//
#include <hip/hip_runtime.h>
#include <hip/hip_bf16.h>
#include <math.h>

#define NN 128
#define TRI 8256          // 128*129/2
#define BATCH 2048
#define M_L 10
#define KAPPA 0.276f

using half8  = __attribute__((ext_vector_type(8))) _Float16;  // MFMA A/B frag (4 VGPRs)
using half2v = __attribute__((ext_vector_type(2))) _Float16;
using f32x4  = __attribute__((ext_vector_type(4))) float;     // MFMA C/D frag

// ---------------------------------------------------------------------------
// fp64 Sturm sign count reading T directly from LDS ab_s (broadcast reads,
// minimal registers -- R15 tail form).
// ---------------------------------------------------------------------------
__device__ inline int sturm_lds(const float* __restrict__ ab_s, double x) {
    double pm = 1.0;
    double p  = (double)ab_s[0] - x;
    int c = (p < 0.0);
    #pragma unroll
    for (int i = 1; i < M_L; i++) {
        double bb = (double)ab_s[10 + i - 1];
        double pn = ((double)ab_s[i] - x) * p - (bb * bb) * pm;
        c += ((pn < 0.0) != (p < 0.0));
        pm = p; p = pn;
    }
    return c;
}

// ---------------------------------------------------------------------------
// Kernel 1: per-batch fused Lanczos + eig tail.
// R17 = R15 with the ONE fix its post-mortem demanded:
//   __launch_bounds__(256, 4). Register ledger (R14-R16 lessons, unified RF,
//   512 regs/wave-slot/SIMD): acc[2][8] = 64 AGPR (structural: in-place
//   M=L*L^T) + ~48 arch VGPR = ~112 <= 128 cap -> NO spill, 4 waves/SIMD --
//   the same occupancy as R13 but without R13's M writeback, Mr hoist, and
//   two setup barriers. R16 proved the kernel is critical-path-bound, not
//   TLP-bound: occupancy 46% ran SLOWER (barriers widened to 8 waves).
//   So: keep 4-wave rendezvous, shorten the path.
// R15: matvec DIRECTLY from MFMA accumulators (M never materialized).
//   Lane (m,g) of wave w holds acc[bi][j][q] = M[16j+m][16*band+4g+q]
//   (band = w, w+4; mapping verified by the R7+ writeback). Per iteration:
//   zj = sum over both bands of acc*y quads, shfl_xor(16,32) over g,
//   lanes<16 write part slice w; wave-0 hub combines 4 slices. M stays fp32.
// R12/R13 tail: lane-split Sturm (wave b&3), branchless brackets.
// R14: XOR-swizzled [128][128] L buffer, branchless stage scatter;
//   LDS = exactly 32768 (ysf/part/ab_s alias the dead L buffer).
// ---------------------------------------------------------------------------
__global__ __launch_bounds__(256, 4) void lanczos_kernel(
    const float* __restrict__ net_out,
    const float* __restrict__ U1,
    const float* __restrict__ v_in,
    float* __restrict__ contrib)   // [BATCH]
{
    __shared__ __align__(16) _Float16 Msh[128 * 128];   // 32768 B exactly (L, swizzled)
    // aliases into Msh, valid only AFTER the post-GEMM barrier (L dead):
    float* ysf  = (float*)Msh;             // 128 f32  (bytes    0..511)
    float* part = (float*)(Msh + 256);     // 512 f32  (bytes  512..2559)
    float* ab_s = (float*)(Msh + 1280);    // 20  f32  (bytes 2560..2639)

    const int b = blockIdx.x;
    const int t = threadIdx.x;
    const int lane = t & 63;
    const int w = t >> 6;       // wave id 0..3

    // ---- issue wave-0 global loads EARLY (latency hides under staging) ----
    float2 vv = {0.f, 0.f}, uu = {0.f, 0.f};
    if (w == 0) {
        vv = *(const float2*)(v_in + (size_t)b * NN + 2 * lane);
        uu = *(const float2*)(U1 + (size_t)b * 128 + 2 * lane);
    }

    // ---- zero Msh (upper triangle must be 0; swizzle is zero-invariant) ----
    {
        unsigned long long* z = (unsigned long long*)Msh;
        #pragma unroll
        for (int k = t; k < 128 * 128 / 4; k += 256) z[k] = 0ULL;
    }
    __syncthreads();

    // ---- stage L: coalesced float4 reads of packed tril, swizzled scatter ----
    // r = floor((sqrt(8e+1)-1)/2) exact for e<=8255 (R13 proof).
    {
        const float4* src4 = (const float4*)(net_out + (size_t)b * TRI);
        for (int q = t; q < TRI / 4; q += 256) {
            float4 f = src4[q];
            const int e = 4 * q;
            float vals[4] = {f.x, f.y, f.z, f.w};
            #pragma unroll
            for (int i = 0; i < 4; i++) {
                int ei = e + i;
                int r = (int)((sqrtf((float)(8 * ei) + 1.0f) - 1.0f) * 0.5f);
                int c = ei - ((r * (r + 1)) >> 1);
                Msh[r * 128 + (c ^ ((r & 7) << 3))] = (_Float16)vals[i];
            }
        }
    }
    __syncthreads();

    // ---- GEMM: M = L * L^T into acc (NO writeback -- M lives in AGPRs) ----
    // row (16*j+m) & 7 == m & 7, so the swizzle term is ((m&7)<<3) throughout.
    const int m = lane & 15;
    const int g = lane >> 4;
    f32x4 acc[2][8];
    {
        const int sw = (m & 7) << 3;
        #pragma unroll
        for (int bi = 0; bi < 2; bi++)
            #pragma unroll
            for (int j = 0; j < 8; j++) acc[bi][j] = (f32x4){0.f, 0.f, 0.f, 0.f};
        const int band0 = w, band1 = w + 4;
        #pragma unroll
        for (int kc = 0; kc < 4; kc++) {
            const int col = (kc * 32 + g * 8) ^ sw;   // 8-half run stays contiguous
            half8 a0 = *(const half8*)&Msh[(16 * band0 + m) * 128 + col];
            half8 a1 = *(const half8*)&Msh[(16 * band1 + m) * 128 + col];
            #pragma unroll
            for (int j = 0; j < 8; j++) {
                half8 bfr = *(const half8*)&Msh[(16 * j + m) * 128 + col];
                acc[0][j] = __builtin_amdgcn_mfma_f32_16x16x32_f16(a0, bfr, acc[0][j], 0, 0, 0);
                acc[1][j] = __builtin_amdgcn_mfma_f32_16x16x32_f16(a1, bfr, acc[1][j], 0, 0, 0);
            }
        }
    }
    __syncthreads();   // ALL L reads complete -> ysf/part/ab_s may alias Msh

    // ---- wave-0 state init: x (2 elems/lane), gauge regs, first y ----
    float x0 = 0.f, x1 = 0.f, p0 = 0.f, p1 = 0.f, beta = 0.f;
    float u0c = 0.f, u1c = 0.f, u0m = 0.f, u1m = 0.f;
    const int l_ip = (lane + 8) & 63;                  // site (i+1, j)
    const int l_jp = (lane & 56) | ((lane + 1) & 7);   // site (i, j+1)
    const int l_im = (lane + 56) & 63;                 // site (i-1, j)
    const int l_jm = (lane & 56) | ((lane + 7) & 7);   // site (i, j-1)

    if (w == 0) {
        float s = vv.x * vv.x + vv.y * vv.y;
        #pragma unroll
        for (int o = 1; o < 64; o <<= 1) s += __shfl_xor(s, o, 64);
        float inv = 1.0f / sqrtf(s);
        x0 = vv.x * inv; x1 = vv.y * inv;
        u0c = uu.x; u1c = uu.y;
        u0m = __shfl(u0c, l_im, 64);   // u0 at (i-1, j)
        u1m = __shfl(u1c, l_jm, 64);   // u1 at (i, j-1)

        // first y = dd(x), stored as f32 (no fp16 rounding)
        float a0 = __shfl(x0, l_ip, 64), a1 = __shfl(x1, l_ip, 64);
        float b0 = __shfl(x0, l_jp, 64), b1 = __shfl(x1, l_jp, 64);
        float c0 = __shfl(x0, l_im, 64), c1 = __shfl(x1, l_im, 64);
        float d0 = __shfl(x0, l_jm, 64), d1 = __shfl(x1, l_jm, 64);
        float y0 = x0 - KAPPA * (u0c * a0 + u1c * b0 + u0m * c0 + u1m * d0);
        float y1 = x1 - KAPPA * (u0c * a1 + u1c * b1 + u0m * c1 + u1m * d1);
        *(float2*)&ysf[2 * lane] = (float2){y0, y1};
    }
    __syncthreads();   // ysf ready

    // =================== loop: 2 barriers per iteration ===================
    for (int it = 0; it < M_L; it++) {
        // ---- all waves: matvec from AGPR-resident M ----
        {
            float4 yb0 = *(const float4*)&ysf[16 * w + 4 * g];        // band0 cols
            float4 yb1 = *(const float4*)&ysf[16 * (w + 4) + 4 * g];  // band1 cols
            float z[8];
            #pragma unroll
            for (int j = 0; j < 8; j++) {
                f32x4 A0 = acc[0][j], A1 = acc[1][j];
                float zj = A0[0] * yb0.x + A0[1] * yb0.y + A0[2] * yb0.z + A0[3] * yb0.w
                         + A1[0] * yb1.x + A1[1] * yb1.y + A1[2] * yb1.z + A1[3] * yb1.w;
                zj += __shfl_xor(zj, 16, 64);   // combine g0<->g1, g2<->g3
                zj += __shfl_xor(zj, 32, 64);   // full g reduction
                z[j] = zj;
            }
            if (lane < 16) {
                #pragma unroll
                for (int j = 0; j < 8; j++) part[w * 128 + 16 * j + lane] = z[j];
            }
        }
        __syncthreads();   // B1: part ready

        // ---- wave 0: combine 4 slices, reduce, update, dd, broadcast y ----
        if (w == 0) {
            float z0 = 0.f, z1 = 0.f;
            #pragma unroll
            for (int ww = 0; ww < 4; ww++) {
                float2 pw = *(const float2*)&part[ww * 128 + 2 * lane];
                z0 += pw.x; z1 += pw.y;
            }

            float s1 = z0 * x0 + z1 * x1;
            float s2 = z0 * z0 + z1 * z1;
            float s3 = z0 * p0 + z1 * p1;
            #pragma unroll
            for (int o = 1; o < 64; o <<= 1) {
                s1 += __shfl_xor(s1, o, 64);
                s2 += __shfl_xor(s2, o, 64);
                s3 += __shfl_xor(s3, o, 64);
            }
            float alpha = s1;
            float b2 = s2 - alpha * alpha - beta * (2.0f * s3 - beta);
            float bn = sqrtf(fmaxf(b2, 0.0f));
            float w0 = z0 - alpha * x0 - beta * p0;
            float w1 = z1 - alpha * x1 - beta * p1;
            float inv = 1.0f / (bn + 1e-30f);
            p0 = x0; p1 = x1;
            x0 = w0 * inv; x1 = w1 * inv;
            beta = bn;
            if (lane == 0) {
                ab_s[it]      = alpha;
                ab_s[10 + it] = bn;
            }

            // dd for next iteration
            float a0 = __shfl(x0, l_ip, 64), a1 = __shfl(x1, l_ip, 64);
            float b0 = __shfl(x0, l_jp, 64), b1 = __shfl(x1, l_jp, 64);
            float c0 = __shfl(x0, l_im, 64), c1 = __shfl(x1, l_im, 64);
            float d0 = __shfl(x0, l_jm, 64), d1 = __shfl(x1, l_jm, 64);
            float y0 = x0 - KAPPA * (u0c * a0 + u1c * b0 + u0m * c0 + u1m * d0);
            float y1 = x1 - KAPPA * (u0c * a1 + u1c * b1 + u0m * c1 + u1m * d1);
            *(float2*)&ysf[2 * lane] = (float2){y0, y1};
        }
        __syncthreads();   // B2: ysf ready for next matvec; also makes ab_s
                           //     visible to ALL waves after the last iter
    }

    // ============ eig tail: ONE wave (b&3), lane-split Sturm ============
    if (w != (b & 3)) return;   // no barriers below this point

    // Gershgorin bounds straight from LDS (broadcast reads, minimal regs)
    double glo = 1e300, ghi = -1e300;
    #pragma unroll
    for (int i = 0; i < M_L; i++) {
        double ai = (double)ab_s[i];
        double rr = 0.0;
        if (i > 0)        rr += fabs((double)ab_s[10 + i - 1]);
        if (i < M_L - 1)  rr += fabs((double)ab_s[10 + i]);
        glo = fmin(glo, ai - rr);
        ghi = fmax(ghi, ai + rr);
    }

    const int kk = lane & 31;
    const bool topHalf = (lane >= 32);

    // Phase 1: lanes 0-31 find lmax (K=10), lanes 32-63 find lmin (K=1);
    // 33-section x 4 rounds; branchless bracket update.
    const int K = topHalf ? 1 : M_L;
    double lo = glo, hi = ghi;
    for (int round = 0; round < 4; round++) {
        double wdt = (hi - lo) * (1.0 / 33.0);
        double x = lo + wdt * (double)(kk + 1);
        int cnt = sturm_lds(ab_s, x);
        unsigned long long m64 = __ballot(cnt >= K);
        unsigned mm = topHalf ? (unsigned)(m64 >> 32)
                              : (unsigned)(m64 & 0xffffffffu);
        int p = (mm == 0u) ? 32 : (__ffs(mm) - 1);
        double nlo = lo + wdt * (double)p;
        hi = (mm == 0u) ? hi : (lo + wdt * (double)(p + 1));
        lo = nlo;
    }
    double mid = 0.5 * (lo + hi);
    double lmax = __shfl(mid, 0, 64);
    double lmin = __shfl(mid, 32, 64);
    double maxabs = fmax(fabs(lmax), fabs(lmin));

    // Phase 2: window |lambda|min -- lanes 0-31 eval +s, lanes 32-63 eval -s;
    // combine via shfl_xor(32); 33-section x 4 rounds; branchless update.
    double wlo = 0.0, whi = maxabs;
    for (int round = 0; round < 4; round++) {
        double wdt = (whi - wlo) * (1.0 / 33.0);
        double s = wlo + wdt * (double)(kk + 1);
        double x = topHalf ? -s : s;
        int cnt = sturm_lds(ab_s, x);
        int o = __shfl_xor(cnt, 32, 64);
        int inwin = topHalf ? (o - cnt) : (cnt - o);
        unsigned long long m64 = __ballot(inwin >= 1);
        unsigned mm = (unsigned)(m64 & 0xffffffffu);   // halves mirror
        int p = (mm == 0u) ? 32 : (__ffs(mm) - 1);
        double nlo = wlo + wdt * (double)p;
        whi = (mm == 0u) ? whi : (wlo + wdt * (double)(p + 1));
        wlo = nlo;
    }
    double minabs = 0.5 * (wlo + whi);
    if (lane == 0) contrib[b] = (float)(maxabs * maxabs - minabs * minabs);
}

// ---------------------------------------------------------------------------
// Kernel 2: reduce 2048 contributions -> d_out[0] (mean)
// ---------------------------------------------------------------------------
__global__ __launch_bounds__(1024) void reduce_kernel(
    const float* __restrict__ contrib, float* __restrict__ out)
{
    __shared__ float red[16];
    int t = threadIdx.x;
    float s = contrib[t] + contrib[t + 1024];
    #pragma unroll
    for (int o = 32; o > 0; o >>= 1) s += __shfl_down(s, o, 64);
    if ((t & 63) == 0) red[t >> 6] = s;
    __syncthreads();
    if (t < 64) {
        float r = (t < 16) ? red[t] : 0.0f;
        #pragma unroll
        for (int o = 8; o > 0; o >>= 1) r += __shfl_down(r, o, 64);
        if (t == 0) out[0] = r / (float)BATCH;
    }
}

extern "C" void kernel_launch(void* const* d_in, const int* in_sizes, int n_in,
                              void* d_out, int out_size, void* d_ws, size_t ws_size,
                              hipStream_t stream) {
    const float* net_out = (const float*)d_in[0];
    const float* U1      = (const float*)d_in[1];
    const float* v       = (const float*)d_in[2];
    float* contrib = (float*)d_ws;   // BATCH floats

    lanczos_kernel<<<BATCH, 256, 0, stream>>>(net_out, U1, v, contrib);
    reduce_kernel<<<1, 1024, 0, stream>>>(contrib, (float*)d_out);
}

// Round 10
// 138.493 us; speedup vs baseline: 1.2520x; 1.0045x over previous
//
#include <hip/hip_runtime.h>
#include <hip/hip_bf16.h>
#include <math.h>

#define NN 128
#define TRI 8256          // 128*129/2
#define BATCH 2048
#define M_L 10
#define KAPPA 0.276f
#define LDL 136           // padded row stride (fp16): 17 quads/row, 16B-aligned rows

using half8  = __attribute__((ext_vector_type(8))) _Float16;  // MFMA A/B frag (4 VGPRs)
using half2v = __attribute__((ext_vector_type(2))) _Float16;
using f32x4  = __attribute__((ext_vector_type(4))) float;     // MFMA C/D frag

static __device__ inline float dot2h(unsigned m, unsigned y, float c) {
#if __has_builtin(__builtin_amdgcn_fdot2)
    return __builtin_amdgcn_fdot2(__builtin_bit_cast(half2v, m),
                                  __builtin_bit_cast(half2v, y), c, false);
#else
    half2v a = __builtin_bit_cast(half2v, m), b = __builtin_bit_cast(half2v, y);
    return c + (float)a.x * (float)b.x + (float)a.y * (float)b.y;
#endif
}

// ---------------------------------------------------------------------------
// fp64 Sturm sign count reading T from LDS ab_s (broadcast reads, minimal
// registers -- R15/R17-verified form; guard-free per R13 range argument).
// ---------------------------------------------------------------------------
__device__ inline int sturm_lds(const float* __restrict__ ab_s, double x) {
    double pm = 1.0;
    double p  = (double)ab_s[0] - x;
    int c = (p < 0.0);
    #pragma unroll
    for (int i = 1; i < M_L; i++) {
        double bb = (double)ab_s[10 + i - 1];
        double pn = ((double)ab_s[i] - x) * p - (bb * bb) * pm;
        c += ((pn < 0.0) != (p < 0.0));
        pm = p; p = pn;
    }
    return c;
}

// ---------------------------------------------------------------------------
// Kernel 1: per-batch fused Lanczos + eig tail.
// R18 = R13 (best verified: Mr-regs dot2h loop) with the hub DE-SERIALIZED,
// provably race-free (unlike failed R11a):
//   * every wave computes the hub REPLICATED (identical inputs + identical
//     instruction sequence per wave -> bit-identical FP results) and writes
//     y to a PRIVATE slice ysw[w][*]; each thread's matvec reads only its
//     own wave's slice. No cross-wave y communication at all.
//   * the only cross-wave LDS edge is part[], double-buffered part[2][256]
//     across the single barrier. Max skew = 1 window; fast wave touches
//     part[(it+1)&1] + ysw[own] only -- disjoint from slow wave's reads.
//   * ab_s has a SINGLE writer (tail wave b&3, lane 0) and is read by that
//     same wave in the tail -> no barrier, no race.
//   -> ONE barrier per iteration (was 2), no idle-wait behind the hub.
// R9: M half-row in registers (8x uint4). R10: fused eig tail.
// R12: lane-split Sturm (wave b&3). R13: branchless stage/brackets.
// R16/R17 lessons: critical-path-bound (not TLP); AGPR-matvec form worse.
// ---------------------------------------------------------------------------
__global__ __launch_bounds__(256, 4) void lanczos_kernel(
    const float* __restrict__ net_out,
    const float* __restrict__ U1,
    const float* __restrict__ v_in,
    float* __restrict__ contrib)   // [BATCH]
{
    __shared__ __align__(16) _Float16 Lsq[128 * LDL];  // 34KB: L, then M (in-place)
    __shared__ __align__(16) unsigned ysw[4][64];      // per-wave y replicas (fp16x2)
    __shared__ __align__(16) float part[2][256];       // matvec partials, dbuf
    __shared__ __align__(16) float ab_s[20];           // alpha[10], beta[10]

    const int b = blockIdx.x;
    const int t = threadIdx.x;
    const int lane = t & 63;
    const int w = t >> 6;       // wave id 0..3
    const int tw = b & 3;       // tail wave (spreads fp64 across SIMDs)

    // ---- ALL waves load vv/uu early (replicated state; L2 dedups) ----
    float2 vv = *(const float2*)(v_in + (size_t)b * NN + 2 * lane);
    float2 uu = *(const float2*)(U1 + (size_t)b * 128 + 2 * lane);

    // ---- zero Lsq (upper triangle + padding) ----
    {
        unsigned long long* z = (unsigned long long*)Lsq;
        #pragma unroll
        for (int k = t; k < 128 * LDL / 4; k += 256) z[k] = 0ULL;
    }
    __syncthreads();

    // ---- stage L: coalesced float4 reads of packed tril, scatter fp16 ----
    // r = floor((sqrt(8e+1)-1)/2) exact for e<=8255 (R13 proof).
    {
        const float4* src4 = (const float4*)(net_out + (size_t)b * TRI);
        for (int q = t; q < TRI / 4; q += 256) {
            float4 f = src4[q];
            const int e = 4 * q;
            float vals[4] = {f.x, f.y, f.z, f.w};
            #pragma unroll
            for (int i = 0; i < 4; i++) {
                int ei = e + i;
                int r = (int)((sqrtf((float)(8 * ei) + 1.0f) - 1.0f) * 0.5f);
                int c = ei - ((r * (r + 1)) >> 1);
                Lsq[r * LDL + c] = (_Float16)vals[i];
            }
        }
    }
    __syncthreads();

    // ---- GEMM: M = L * L^T (16x16x32 f16 MFMA; wave w: bands w, w+4) ----
    {
        const int m = lane & 15;
        const int g = lane >> 4;
        f32x4 acc[2][8];
        #pragma unroll
        for (int bi = 0; bi < 2; bi++)
            #pragma unroll
            for (int j = 0; j < 8; j++) acc[bi][j] = (f32x4){0.f, 0.f, 0.f, 0.f};
        const int band0 = w, band1 = w + 4;
        #pragma unroll
        for (int kc = 0; kc < 4; kc++) {
            const int col = kc * 32 + g * 8;
            half8 a0 = *(const half8*)&Lsq[(16 * band0 + m) * LDL + col];
            half8 a1 = *(const half8*)&Lsq[(16 * band1 + m) * LDL + col];
            #pragma unroll
            for (int j = 0; j < 8; j++) {
                half8 bfr = *(const half8*)&Lsq[(16 * j + m) * LDL + col];
                acc[0][j] = __builtin_amdgcn_mfma_f32_16x16x32_f16(a0, bfr, acc[0][j], 0, 0, 0);
                acc[1][j] = __builtin_amdgcn_mfma_f32_16x16x32_f16(a1, bfr, acc[1][j], 0, 0, 0);
            }
        }
        __syncthreads();   // ALL Lsq reads complete before in-place overwrite

        #pragma unroll
        for (int bi = 0; bi < 2; bi++) {
            const int band = (bi == 0) ? band0 : band1;
            #pragma unroll
            for (int j = 0; j < 8; j++) {
                f32x4 a = acc[bi][j];
                half2v p01 = {(_Float16)a[0], (_Float16)a[1]};
                half2v p23 = {(_Float16)a[2], (_Float16)a[3]};
                uint2 pk;
                pk.x = __builtin_bit_cast(unsigned, p01);
                pk.y = __builtin_bit_cast(unsigned, p23);
                *(uint2*)&Lsq[(16 * j + m) * LDL + 16 * band + 4 * g] = pk;
            }
        }
    }
    __syncthreads();   // M ready in Lsq

    // ---- hoist this thread's half-row of M into registers (one time) ----
    const int r = t & 127, h = t >> 7;
    uint4 Mr[8];
    {
        const uint4* M4 = (const uint4*)&Lsq[r * LDL + 64 * h];
        #pragma unroll
        for (int c = 0; c < 8; c++) Mr[c] = M4[c];
    }
    // ysw/part/ab_s are separate LDS arrays (no aliasing) -> no barrier here.

    // ---- replicated state init (ALL waves, identical -> deterministic) ----
    const int l_ip = (lane + 8) & 63;                  // site (i+1, j)
    const int l_jp = (lane & 56) | ((lane + 1) & 7);   // site (i, j+1)
    const int l_im = (lane + 56) & 63;                 // site (i-1, j)
    const int l_jm = (lane & 56) | ((lane + 7) & 7);   // site (i, j-1)

    float x0, x1, p0 = 0.f, p1 = 0.f, beta = 0.f;
    const float u0c = uu.x, u1c = uu.y;
    const float u0m = __shfl(u0c, l_im, 64);   // u0 at (i-1, j)
    const float u1m = __shfl(u1c, l_jm, 64);   // u1 at (i, j-1)
    {
        float s = vv.x * vv.x + vv.y * vv.y;
        #pragma unroll
        for (int o = 1; o < 64; o <<= 1) s += __shfl_xor(s, o, 64);
        float inv = 1.0f / sqrtf(s);
        x0 = vv.x * inv; x1 = vv.y * inv;

        // first y = dd(x) -> OWN wave slice (own-wave program order suffices)
        float a0 = __shfl(x0, l_ip, 64), a1 = __shfl(x1, l_ip, 64);
        float b0 = __shfl(x0, l_jp, 64), b1 = __shfl(x1, l_jp, 64);
        float c0 = __shfl(x0, l_im, 64), c1 = __shfl(x1, l_im, 64);
        float d0 = __shfl(x0, l_jm, 64), d1 = __shfl(x1, l_jm, 64);
        float y0 = x0 - KAPPA * (u0c * a0 + u1c * b0 + u0m * c0 + u1m * d0);
        float y1 = x1 - KAPPA * (u0c * a1 + u1c * b1 + u0m * c1 + u1m * d1);
        half2v yp = {(_Float16)y0, (_Float16)y1};
        ysw[w][lane] = __builtin_bit_cast(unsigned, yp);
    }

    // =================== loop: ONE barrier per iteration ===================
    const uint4* Y4 = (const uint4*)&ysw[w][32 * h];   // own-wave slice only

    for (int it = 0; it < M_L; it++) {
        // ---- all threads: half-row matvec from registers, 4 accumulators ----
        {
            float aA = 0.f, aB = 0.f, aC = 0.f, aD = 0.f;
            #pragma unroll
            for (int c = 0; c < 8; c += 4) {
                uint4 y_0 = Y4[c],     y_1 = Y4[c + 1];
                uint4 y_2 = Y4[c + 2], y_3 = Y4[c + 3];
                aA = dot2h(Mr[c].x,     y_0.x, aA); aA = dot2h(Mr[c].y,     y_0.y, aA);
                aA = dot2h(Mr[c].z,     y_0.z, aA); aA = dot2h(Mr[c].w,     y_0.w, aA);
                aB = dot2h(Mr[c + 1].x, y_1.x, aB); aB = dot2h(Mr[c + 1].y, y_1.y, aB);
                aB = dot2h(Mr[c + 1].z, y_1.z, aB); aB = dot2h(Mr[c + 1].w, y_1.w, aB);
                aC = dot2h(Mr[c + 2].x, y_2.x, aC); aC = dot2h(Mr[c + 2].y, y_2.y, aC);
                aC = dot2h(Mr[c + 2].z, y_2.z, aC); aC = dot2h(Mr[c + 2].w, y_2.w, aC);
                aD = dot2h(Mr[c + 3].x, y_3.x, aD); aD = dot2h(Mr[c + 3].y, y_3.y, aD);
                aD = dot2h(Mr[c + 3].z, y_3.z, aD); aD = dot2h(Mr[c + 3].w, y_3.w, aD);
            }
            part[it & 1][t] = (aA + aB) + (aC + aD);
        }
        __syncthreads();   // the ONLY barrier: part[it&1] ready for all waves

        // ---- replicated hub (ALL waves; identical work -> identical values) ----
        {
            float2 pa = *(const float2*)&part[it & 1][2 * lane];
            float2 pb = *(const float2*)&part[it & 1][128 + 2 * lane];
            float z0 = pa.x + pb.x;     // z[2*lane]
            float z1 = pa.y + pb.y;     // z[2*lane+1]

            float s1 = z0 * x0 + z1 * x1;
            float s2 = z0 * z0 + z1 * z1;
            float s3 = z0 * p0 + z1 * p1;
            #pragma unroll
            for (int o = 1; o < 64; o <<= 1) {
                s1 += __shfl_xor(s1, o, 64);
                s2 += __shfl_xor(s2, o, 64);
                s3 += __shfl_xor(s3, o, 64);
            }
            float alpha = s1;
            float b2 = s2 - alpha * alpha - beta * (2.0f * s3 - beta);
            float bn = sqrtf(fmaxf(b2, 0.0f));
            float w0 = z0 - alpha * x0 - beta * p0;
            float w1 = z1 - alpha * x1 - beta * p1;
            float inv = 1.0f / (bn + 1e-30f);
            p0 = x0; p1 = x1;
            x0 = w0 * inv; x1 = w1 * inv;
            beta = bn;
            if (w == tw && lane == 0) {   // SINGLE writer: the tail wave
                ab_s[it]      = alpha;
                ab_s[10 + it] = bn;
            }

            // dd for next iteration -> OWN wave slice
            float a0 = __shfl(x0, l_ip, 64), a1 = __shfl(x1, l_ip, 64);
            float b0 = __shfl(x0, l_jp, 64), b1 = __shfl(x1, l_jp, 64);
            float c0 = __shfl(x0, l_im, 64), c1 = __shfl(x1, l_im, 64);
            float d0 = __shfl(x0, l_jm, 64), d1 = __shfl(x1, l_jm, 64);
            float y0 = x0 - KAPPA * (u0c * a0 + u1c * b0 + u0m * c0 + u1m * d0);
            float y1 = x1 - KAPPA * (u0c * a1 + u1c * b1 + u0m * c1 + u1m * d1);
            half2v yp = {(_Float16)y0, (_Float16)y1};
            ysw[w][lane] = __builtin_bit_cast(unsigned, yp);
        }
        // no second barrier: next matvec reads OWN wave's ysw slice
    }

    // ============ eig tail: the single-writer wave reads its own ab_s ============
    if (w != tw) return;   // no barriers below this point

    // Gershgorin bounds straight from LDS (broadcast reads, minimal regs)
    double glo = 1e300, ghi = -1e300;
    #pragma unroll
    for (int i = 0; i < M_L; i++) {
        double ai = (double)ab_s[i];
        double rr = 0.0;
        if (i > 0)        rr += fabs((double)ab_s[10 + i - 1]);
        if (i < M_L - 1)  rr += fabs((double)ab_s[10 + i]);
        glo = fmin(glo, ai - rr);
        ghi = fmax(ghi, ai + rr);
    }

    const int kk = lane & 31;
    const bool topHalf = (lane >= 32);

    // Phase 1: lanes 0-31 find lmax (K=10), lanes 32-63 find lmin (K=1);
    // 33-section x 4 rounds; branchless bracket update.
    const int K = topHalf ? 1 : M_L;
    double lo = glo, hi = ghi;
    for (int round = 0; round < 4; round++) {
        double wdt = (hi - lo) * (1.0 / 33.0);
        double x = lo + wdt * (double)(kk + 1);
        int cnt = sturm_lds(ab_s, x);
        unsigned long long m64 = __ballot(cnt >= K);
        unsigned mm = topHalf ? (unsigned)(m64 >> 32)
                              : (unsigned)(m64 & 0xffffffffu);
        int p = (mm == 0u) ? 32 : (__ffs(mm) - 1);
        double nlo = lo + wdt * (double)p;
        hi = (mm == 0u) ? hi : (lo + wdt * (double)(p + 1));
        lo = nlo;
    }
    double mid = 0.5 * (lo + hi);
    double lmax = __shfl(mid, 0, 64);
    double lmin = __shfl(mid, 32, 64);
    double maxabs = fmax(fabs(lmax), fabs(lmin));

    // Phase 2: window |lambda|min -- lanes 0-31 eval +s, lanes 32-63 eval -s;
    // combine via shfl_xor(32); 33-section x 4 rounds; branchless update.
    double wlo = 0.0, whi = maxabs;
    for (int round = 0; round < 4; round++) {
        double wdt = (whi - wlo) * (1.0 / 33.0);
        double s = wlo + wdt * (double)(kk + 1);
        double x = topHalf ? -s : s;
        int cnt = sturm_lds(ab_s, x);
        int o = __shfl_xor(cnt, 32, 64);
        int inwin = topHalf ? (o - cnt) : (cnt - o);
        unsigned long long m64 = __ballot(inwin >= 1);
        unsigned mm = (unsigned)(m64 & 0xffffffffu);   // halves mirror
        int p = (mm == 0u) ? 32 : (__ffs(mm) - 1);
        double nlo = wlo + wdt * (double)p;
        whi = (mm == 0u) ? whi : (wlo + wdt * (double)(p + 1));
        wlo = nlo;
    }
    double minabs = 0.5 * (wlo + whi);
    if (lane == 0) contrib[b] = (float)(maxabs * maxabs - minabs * minabs);
}

// ---------------------------------------------------------------------------
// Kernel 2: reduce 2048 contributions -> d_out[0] (mean)
// ---------------------------------------------------------------------------
__global__ __launch_bounds__(1024) void reduce_kernel(
    const float* __restrict__ contrib, float* __restrict__ out)
{
    __shared__ float red[16];
    int t = threadIdx.x;
    float s = contrib[t] + contrib[t + 1024];
    #pragma unroll
    for (int o = 32; o > 0; o >>= 1) s += __shfl_down(s, o, 64);
    if ((t & 63) == 0) red[t >> 6] = s;
    __syncthreads();
    if (t < 64) {
        float r = (t < 16) ? red[t] : 0.0f;
        #pragma unroll
        for (int o = 8; o > 0; o >>= 1) r += __shfl_down(r, o, 64);
        if (t == 0) out[0] = r / (float)BATCH;
    }
}

extern "C" void kernel_launch(void* const* d_in, const int* in_sizes, int n_in,
                              void* d_out, int out_size, void* d_ws, size_t ws_size,
                              hipStream_t stream) {
    const float* net_out = (const float*)d_in[0];
    const float* U1      = (const float*)d_in[1];
    const float* v       = (const float*)d_in[2];
    float* contrib = (float*)d_ws;   // BATCH floats

    lanczos_kernel<<<BATCH, 256, 0, stream>>>(net_out, U1, v, contrib);
    reduce_kernel<<<1, 1024, 0, stream>>>(contrib, (float*)d_out);
}

// Round 11
// 130.592 us; speedup vs baseline: 1.3277x; 1.0605x over previous
//
#include <hip/hip_runtime.h>
#include <hip/hip_bf16.h>
#include <math.h>

#define NN 128
#define TRI 8256          // 128*129/2
#define BATCH 2048
#define M_L 10
#define KAPPA 0.276f
#define LDL 136           // padded row stride (fp16): 17 quads/row, 16B-aligned rows

using half8  = __attribute__((ext_vector_type(8))) _Float16;  // MFMA A/B frag (4 VGPRs)
using half2v = __attribute__((ext_vector_type(2))) _Float16;
using f32x4  = __attribute__((ext_vector_type(4))) float;     // MFMA C/D frag

static __device__ inline float dot2h(unsigned m, unsigned y, float c) {
#if __has_builtin(__builtin_amdgcn_fdot2)
    return __builtin_amdgcn_fdot2(__builtin_bit_cast(half2v, m),
                                  __builtin_bit_cast(half2v, y), c, false);
#else
    half2v a = __builtin_bit_cast(half2v, m), b = __builtin_bit_cast(half2v, y);
    return c + (float)a.x * (float)b.x + (float)a.y * (float)b.y;
#endif
}

// ---------------------------------------------------------------------------
// fp64 Sturm sign count.
// Overflow guard removed (R13): |T| entries <= ~3e3 (Gershgorin on L L^T dd,
// L~N(0,1)); |p| products stay within [1e-27, 6e37], far from 1e+/-150.
// ---------------------------------------------------------------------------
__device__ inline int sturm_count10(const double* a, const double* off2, double x) {
    double pm = 1.0;
    double p  = a[0] - x;
    int c = (p < 0.0);
    #pragma unroll
    for (int i = 1; i < M_L; i++) {
        double pn = (a[i] - x) * p - off2[i - 1] * pm;
        c += ((pn < 0.0) != (p < 0.0));
        pm = p; p = pn;
    }
    return c;
}

// ---------------------------------------------------------------------------
// FINAL (R19 = R13, the measured optimum of this structure family).
// Session map (lanczos µs): R13=55 | R14 occupancy/LDS-diet=68 (spill;
// unified RF: 64 AGPR acc is structural) | R15/R17 AGPR-matvec=65 |
// R16 8-wave=110 (critical-path-bound, NOT TLP-bound) | R18 replicated-hub
// 1-barrier=74 (hub's ~26 cross-lane shuffles x4 waves outweigh barriers).
// Counters at this point: HBM 8%, MFMA 6%, VALU 44%, Occ 35% -- a latency/
// serialization floor; every structural exit measured worse.
//
// Structure: per-batch block (256 thr), wave-0-hub Lanczos + fused eig tail.
//   stage L (fp16, branchless exact tril indexing) -> M = L*L^T via MFMA
//   in-place in LDS -> M half-row hoisted to registers (8x uint4/thread) ->
//   10 iters x { all-thread dot2h matvec -> B1 -> wave-0 hub (triple
//   butterfly, state update, dd via shuffles, y broadcast) -> B2 } ->
//   lane-split fp64 Sturm tail on wave b&3 (lmax/lmin simultaneous in lane
//   halves; +/-s window with shfl_xor combine; branchless brackets).
// ---------------------------------------------------------------------------
__global__ __launch_bounds__(256, 4) void lanczos_kernel(
    const float* __restrict__ net_out,
    const float* __restrict__ U1,
    const float* __restrict__ v_in,
    float* __restrict__ contrib)   // [BATCH]
{
    __shared__ __align__(16) _Float16 Lsq[128 * LDL];  // 34KB: L, then M (in-place)
    __shared__ __align__(16) unsigned ys[64];          // y broadcast (128 fp16)
    __shared__ __align__(16) float part[256];          // matvec half-row partials
    __shared__ __align__(16) float ab_s[20];           // alpha[10], beta[10]

    const int b = blockIdx.x;
    const int t = threadIdx.x;
    const int lane = t & 63;
    const int w = t >> 6;       // wave id 0..3

    // ---- issue wave-0 global loads EARLY (latency hides under staging) ----
    float2 vv = {0.f, 0.f}, uu = {0.f, 0.f};
    if (w == 0) {
        vv = *(const float2*)(v_in + (size_t)b * NN + 2 * lane);
        uu = *(const float2*)(U1 + (size_t)b * 128 + 2 * lane);
    }

    // ---- zero Lsq (upper triangle + padding) ----
    {
        unsigned long long* z = (unsigned long long*)Lsq;
        #pragma unroll
        for (int k = t; k < 128 * LDL / 4; k += 256) z[k] = 0ULL;
    }
    __syncthreads();

    // ---- stage L: coalesced float4 reads of packed tril, scatter fp16 ----
    // r = floor((sqrt(8e+1)-1)/2) is EXACT for e<=8255: at triangular e,
    // 1+8e=(2r+1)^2 is an exact fp32 square (<=66049<2^24); between them the
    // margin >=0.015 >> 3e-5 fp error.
    {
        const float4* src4 = (const float4*)(net_out + (size_t)b * TRI);
        for (int q = t; q < TRI / 4; q += 256) {
            float4 f = src4[q];
            const int e = 4 * q;
            float vals[4] = {f.x, f.y, f.z, f.w};
            #pragma unroll
            for (int i = 0; i < 4; i++) {
                int ei = e + i;
                int r = (int)((sqrtf((float)(8 * ei) + 1.0f) - 1.0f) * 0.5f);
                int c = ei - ((r * (r + 1)) >> 1);
                Lsq[r * LDL + c] = (_Float16)vals[i];
            }
        }
    }
    __syncthreads();

    // ---- GEMM: M = L * L^T (16x16x32 f16 MFMA; wave w: bands w, w+4) ----
    {
        const int m = lane & 15;
        const int g = lane >> 4;
        f32x4 acc[2][8];
        #pragma unroll
        for (int bi = 0; bi < 2; bi++)
            #pragma unroll
            for (int j = 0; j < 8; j++) acc[bi][j] = (f32x4){0.f, 0.f, 0.f, 0.f};
        const int band0 = w, band1 = w + 4;
        #pragma unroll
        for (int kc = 0; kc < 4; kc++) {
            const int col = kc * 32 + g * 8;
            half8 a0 = *(const half8*)&Lsq[(16 * band0 + m) * LDL + col];
            half8 a1 = *(const half8*)&Lsq[(16 * band1 + m) * LDL + col];
            #pragma unroll
            for (int j = 0; j < 8; j++) {
                half8 bfr = *(const half8*)&Lsq[(16 * j + m) * LDL + col];
                acc[0][j] = __builtin_amdgcn_mfma_f32_16x16x32_f16(a0, bfr, acc[0][j], 0, 0, 0);
                acc[1][j] = __builtin_amdgcn_mfma_f32_16x16x32_f16(a1, bfr, acc[1][j], 0, 0, 0);
            }
        }
        __syncthreads();   // ALL Lsq reads complete before in-place overwrite

        #pragma unroll
        for (int bi = 0; bi < 2; bi++) {
            const int band = (bi == 0) ? band0 : band1;
            #pragma unroll
            for (int j = 0; j < 8; j++) {
                f32x4 a = acc[bi][j];
                half2v p01 = {(_Float16)a[0], (_Float16)a[1]};
                half2v p23 = {(_Float16)a[2], (_Float16)a[3]};
                uint2 pk;
                pk.x = __builtin_bit_cast(unsigned, p01);
                pk.y = __builtin_bit_cast(unsigned, p23);
                *(uint2*)&Lsq[(16 * j + m) * LDL + 16 * band + 4 * g] = pk;
            }
        }
    }
    __syncthreads();   // M ready in Lsq

    // ---- hoist this thread's half-row of M into registers (one time) ----
    const int r = t & 127, h = t >> 7;
    uint4 Mr[8];
    {
        const uint4* M4 = (const uint4*)&Lsq[r * LDL + 64 * h];
        #pragma unroll
        for (int c = 0; c < 8; c++) Mr[c] = M4[c];
    }

    // ---- wave-0 state init: x (2 elems/lane), gauge regs, first y ----
    float x0 = 0.f, x1 = 0.f, p0 = 0.f, p1 = 0.f, beta = 0.f;
    float u0c = 0.f, u1c = 0.f, u0m = 0.f, u1m = 0.f;
    const int l_ip = (lane + 8) & 63;                  // site (i+1, j)
    const int l_jp = (lane & 56) | ((lane + 1) & 7);   // site (i, j+1)
    const int l_im = (lane + 56) & 63;                 // site (i-1, j)
    const int l_jm = (lane & 56) | ((lane + 7) & 7);   // site (i, j-1)

    if (w == 0) {
        float s = vv.x * vv.x + vv.y * vv.y;
        #pragma unroll
        for (int o = 1; o < 64; o <<= 1) s += __shfl_xor(s, o, 64);
        float inv = 1.0f / sqrtf(s);
        x0 = vv.x * inv; x1 = vv.y * inv;
        u0c = uu.x; u1c = uu.y;
        u0m = __shfl(u0c, l_im, 64);   // u0 at (i-1, j)
        u1m = __shfl(u1c, l_jm, 64);   // u1 at (i, j-1)

        // first y = dd(x)
        float a0 = __shfl(x0, l_ip, 64), a1 = __shfl(x1, l_ip, 64);
        float b0 = __shfl(x0, l_jp, 64), b1 = __shfl(x1, l_jp, 64);
        float c0 = __shfl(x0, l_im, 64), c1 = __shfl(x1, l_im, 64);
        float d0 = __shfl(x0, l_jm, 64), d1 = __shfl(x1, l_jm, 64);
        float y0 = x0 - KAPPA * (u0c * a0 + u1c * b0 + u0m * c0 + u1m * d0);
        float y1 = x1 - KAPPA * (u0c * a1 + u1c * b1 + u0m * c1 + u1m * d1);
        half2v yp = {(_Float16)y0, (_Float16)y1};
        ys[lane] = __builtin_bit_cast(unsigned, yp);
    }
    __syncthreads();   // ys ready

    // =================== loop: 2 barriers per iteration ===================
    const uint4* Y4 = (const uint4*)&ys[32 * h];

    for (int it = 0; it < M_L; it++) {
        // ---- all threads: half-row matvec from registers, 4 accumulators ----
        {
            float aA = 0.f, aB = 0.f, aC = 0.f, aD = 0.f;
            #pragma unroll
            for (int c = 0; c < 8; c += 4) {
                uint4 y_0 = Y4[c],     y_1 = Y4[c + 1];
                uint4 y_2 = Y4[c + 2], y_3 = Y4[c + 3];
                aA = dot2h(Mr[c].x,     y_0.x, aA); aA = dot2h(Mr[c].y,     y_0.y, aA);
                aA = dot2h(Mr[c].z,     y_0.z, aA); aA = dot2h(Mr[c].w,     y_0.w, aA);
                aB = dot2h(Mr[c + 1].x, y_1.x, aB); aB = dot2h(Mr[c + 1].y, y_1.y, aB);
                aB = dot2h(Mr[c + 1].z, y_1.z, aB); aB = dot2h(Mr[c + 1].w, y_1.w, aB);
                aC = dot2h(Mr[c + 2].x, y_2.x, aC); aC = dot2h(Mr[c + 2].y, y_2.y, aC);
                aC = dot2h(Mr[c + 2].z, y_2.z, aC); aC = dot2h(Mr[c + 2].w, y_2.w, aC);
                aD = dot2h(Mr[c + 3].x, y_3.x, aD); aD = dot2h(Mr[c + 3].y, y_3.y, aD);
                aD = dot2h(Mr[c + 3].z, y_3.z, aD); aD = dot2h(Mr[c + 3].w, y_3.w, aD);
            }
            part[t] = (aA + aB) + (aC + aD);
        }
        __syncthreads();   // B1: part ready

        // ---- wave 0: combine, reduce, update, dd, broadcast y ----
        if (w == 0) {
            float2 pa = *(const float2*)&part[2 * lane];
            float2 pb = *(const float2*)&part[128 + 2 * lane];
            float z0 = pa.x + pb.x;     // z[2*lane]
            float z1 = pa.y + pb.y;     // z[2*lane+1]

            float s1 = z0 * x0 + z1 * x1;
            float s2 = z0 * z0 + z1 * z1;
            float s3 = z0 * p0 + z1 * p1;
            #pragma unroll
            for (int o = 1; o < 64; o <<= 1) {
                s1 += __shfl_xor(s1, o, 64);
                s2 += __shfl_xor(s2, o, 64);
                s3 += __shfl_xor(s3, o, 64);
            }
            float alpha = s1;
            float b2 = s2 - alpha * alpha - beta * (2.0f * s3 - beta);
            float bn = sqrtf(fmaxf(b2, 0.0f));
            float w0 = z0 - alpha * x0 - beta * p0;
            float w1 = z1 - alpha * x1 - beta * p1;
            float inv = 1.0f / (bn + 1e-30f);
            p0 = x0; p1 = x1;
            x0 = w0 * inv; x1 = w1 * inv;
            beta = bn;
            if (lane == 0) {
                ab_s[it]      = alpha;   // LDS scratch, no global round-trip
                ab_s[10 + it] = bn;
            }

            // dd for next iteration
            float a0 = __shfl(x0, l_ip, 64), a1 = __shfl(x1, l_ip, 64);
            float b0 = __shfl(x0, l_jp, 64), b1 = __shfl(x1, l_jp, 64);
            float c0 = __shfl(x0, l_im, 64), c1 = __shfl(x1, l_im, 64);
            float d0 = __shfl(x0, l_jm, 64), d1 = __shfl(x1, l_jm, 64);
            float y0 = x0 - KAPPA * (u0c * a0 + u1c * b0 + u0m * c0 + u1m * d0);
            float y1 = x1 - KAPPA * (u0c * a1 + u1c * b1 + u0m * c1 + u1m * d1);
            half2v yp = {(_Float16)y0, (_Float16)y1};
            ys[lane] = __builtin_bit_cast(unsigned, yp);
        }
        __syncthreads();   // B2: ys ready for next matvec; also makes ab_s
                           //     visible to ALL waves after the last iter
    }

    // ============ eig tail: ONE wave (b&3), lane-split Sturm ============
    if (w != (b & 3)) return;   // no barriers below this point

    double a[M_L], off2[M_L - 1], offa[M_L - 1];
    #pragma unroll
    for (int i = 0; i < M_L; i++) a[i] = (double)ab_s[i];
    #pragma unroll
    for (int i = 0; i < M_L - 1; i++) {
        double bb = (double)ab_s[10 + i];
        offa[i] = fabs(bb);
        off2[i] = bb * bb;
    }
    double glo = 1e300, ghi = -1e300;
    #pragma unroll
    for (int i = 0; i < M_L; i++) {
        double rr = 0.0;
        if (i > 0) rr += offa[i - 1];
        if (i < M_L - 1) rr += offa[i];
        glo = fmin(glo, a[i] - rr);
        ghi = fmax(ghi, a[i] + rr);
    }

    const int kk = lane & 31;
    const bool topHalf = (lane >= 32);

    // Phase 1: lanes 0-31 find lmax (K=10), lanes 32-63 find lmin (K=1);
    // 33-section x 4 rounds; branchless bracket update (p=32 = "none").
    const int K = topHalf ? 1 : M_L;
    double lo = glo, hi = ghi;
    for (int round = 0; round < 4; round++) {
        double wdt = (hi - lo) * (1.0 / 33.0);
        double x = lo + wdt * (double)(kk + 1);
        int cnt = sturm_count10(a, off2, x);
        unsigned long long m64 = __ballot(cnt >= K);
        unsigned mm = topHalf ? (unsigned)(m64 >> 32)
                              : (unsigned)(m64 & 0xffffffffu);
        int p = (mm == 0u) ? 32 : (__ffs(mm) - 1);
        double nlo = lo + wdt * (double)p;
        hi = (mm == 0u) ? hi : (lo + wdt * (double)(p + 1));
        lo = nlo;
    }
    double mid = 0.5 * (lo + hi);
    double lmax = __shfl(mid, 0, 64);
    double lmin = __shfl(mid, 32, 64);
    double maxabs = fmax(fabs(lmax), fabs(lmin));

    // Phase 2: window |lambda|min -- lanes 0-31 eval +s, lanes 32-63 eval -s
    // at mirrored s; combine via shfl_xor(32); 33-section x 4 rounds.
    double wlo = 0.0, whi = maxabs;
    for (int round = 0; round < 4; round++) {
        double wdt = (whi - wlo) * (1.0 / 33.0);
        double s = wlo + wdt * (double)(kk + 1);
        double x = topHalf ? -s : s;
        int cnt = sturm_count10(a, off2, x);
        int o = __shfl_xor(cnt, 32, 64);
        int inwin = topHalf ? (o - cnt) : (cnt - o);
        unsigned long long m64 = __ballot(inwin >= 1);
        unsigned mm = (unsigned)(m64 & 0xffffffffu);   // halves mirror
        int p = (mm == 0u) ? 32 : (__ffs(mm) - 1);
        double nlo = wlo + wdt * (double)p;
        whi = (mm == 0u) ? whi : (wlo + wdt * (double)(p + 1));
        wlo = nlo;
    }
    double minabs = 0.5 * (wlo + whi);
    if (lane == 0) contrib[b] = (float)(maxabs * maxabs - minabs * minabs);
}

// ---------------------------------------------------------------------------
// Kernel 2: reduce 2048 contributions -> d_out[0] (mean)
// ---------------------------------------------------------------------------
__global__ __launch_bounds__(1024) void reduce_kernel(
    const float* __restrict__ contrib, float* __restrict__ out)
{
    __shared__ float red[16];
    int t = threadIdx.x;
    float s = contrib[t] + contrib[t + 1024];
    #pragma unroll
    for (int o = 32; o > 0; o >>= 1) s += __shfl_down(s, o, 64);
    if ((t & 63) == 0) red[t >> 6] = s;
    __syncthreads();
    if (t < 64) {
        float r = (t < 16) ? red[t] : 0.0f;
        #pragma unroll
        for (int o = 8; o > 0; o >>= 1) r += __shfl_down(r, o, 64);
        if (t == 0) out[0] = r / (float)BATCH;
    }
}

extern "C" void kernel_launch(void* const* d_in, const int* in_sizes, int n_in,
                              void* d_out, int out_size, void* d_ws, size_t ws_size,
                              hipStream_t stream) {
    const float* net_out = (const float*)d_in[0];
    const float* U1      = (const float*)d_in[1];
    const float* v       = (const float*)d_in[2];
    float* contrib = (float*)d_ws;   // BATCH floats

    lanczos_kernel<<<BATCH, 256, 0, stream>>>(net_out, U1, v, contrib);
    reduce_kernel<<<1, 1024, 0, stream>>>(contrib, (float*)d_out);
}

// Round 12
// 129.881 us; speedup vs baseline: 1.3350x; 1.0055x over previous
//
#include <hip/hip_runtime.h>
#include <hip/hip_bf16.h>
#include <math.h>

#define NN 128
#define TRI 8256          // 128*129/2
#define BATCH 2048
#define M_L 10
#define KAPPA 0.276f
#define LDL 136           // padded row stride (fp16): 17 quads/row, 16B-aligned rows

using half8  = __attribute__((ext_vector_type(8))) _Float16;  // MFMA A/B frag (4 VGPRs)
using half2v = __attribute__((ext_vector_type(2))) _Float16;
using f32x4  = __attribute__((ext_vector_type(4))) float;     // MFMA C/D frag

static __device__ inline float dot2h(unsigned m, unsigned y, float c) {
#if __has_builtin(__builtin_amdgcn_fdot2)
    return __builtin_amdgcn_fdot2(__builtin_bit_cast(half2v, m),
                                  __builtin_bit_cast(half2v, y), c, false);
#else
    half2v a = __builtin_bit_cast(half2v, m), b = __builtin_bit_cast(half2v, y);
    return c + (float)a.x * (float)b.x + (float)a.y * (float)b.y;
#endif
}

// ---------------------------------------------------------------------------
// fp64 Sturm sign count.
// Overflow guard removed (R13): |T| entries <= ~3e3 (Gershgorin on L L^T dd,
// L~N(0,1)); |p| products stay within [1e-27, 6e37], far from 1e+/-150.
// ---------------------------------------------------------------------------
__device__ inline int sturm_count10(const double* a, const double* off2, double x) {
    double pm = 1.0;
    double p  = a[0] - x;
    int c = (p < 0.0);
    #pragma unroll
    for (int i = 1; i < M_L; i++) {
        double pn = (a[i] - x) * p - off2[i - 1] * pm;
        c += ((pn < 0.0) != (p < 0.0));
        pm = p; p = pn;
    }
    return c;
}

// ---------------------------------------------------------------------------
// R20 = R19 (verified optimum) + s_setprio(1) on the two SERIAL critical
// sections: the wave-0 hub (per iteration) and the 1-wave fp64 Sturm tail.
// Mechanism (T5, m191 attn-topology): during a block's serial section, the
// SIMD also hosts OTHER blocks' throughput-bound matvec waves (dot2h = 75%
// of VALU issue, latency-tolerant). Default arbitration makes the critical
// path wait behind work that has slack; priority shortens the serialized
// section. This kernel matches the attn case (independent blocks, serial
// hub wave), NOT the m190 lockstep-GEMM null case.
//
// Session map (lanczos µs): R13/R19=55 | R14 LDS-diet=68 (spill; unified RF,
// 64-AGPR acc structural) | R15/R17 AGPR-matvec=65 | R16 8-wave=110
// (critical-path-bound, NOT TLP-bound) | R18 replicated-hub=74 (hub shuffle
// cost x4 outweighs barrier savings). Counters: HBM 8%, MFMA 6%, VALU 43%,
// Occ 34% -- latency/serialization floor; all structural exits measured worse.
// ---------------------------------------------------------------------------
__global__ __launch_bounds__(256, 4) void lanczos_kernel(
    const float* __restrict__ net_out,
    const float* __restrict__ U1,
    const float* __restrict__ v_in,
    float* __restrict__ contrib)   // [BATCH]
{
    __shared__ __align__(16) _Float16 Lsq[128 * LDL];  // 34KB: L, then M (in-place)
    __shared__ __align__(16) unsigned ys[64];          // y broadcast (128 fp16)
    __shared__ __align__(16) float part[256];          // matvec half-row partials
    __shared__ __align__(16) float ab_s[20];           // alpha[10], beta[10]

    const int b = blockIdx.x;
    const int t = threadIdx.x;
    const int lane = t & 63;
    const int w = t >> 6;       // wave id 0..3

    // ---- issue wave-0 global loads EARLY (latency hides under staging) ----
    float2 vv = {0.f, 0.f}, uu = {0.f, 0.f};
    if (w == 0) {
        vv = *(const float2*)(v_in + (size_t)b * NN + 2 * lane);
        uu = *(const float2*)(U1 + (size_t)b * 128 + 2 * lane);
    }

    // ---- zero Lsq (upper triangle + padding) ----
    {
        unsigned long long* z = (unsigned long long*)Lsq;
        #pragma unroll
        for (int k = t; k < 128 * LDL / 4; k += 256) z[k] = 0ULL;
    }
    __syncthreads();

    // ---- stage L: coalesced float4 reads of packed tril, scatter fp16 ----
    // r = floor((sqrt(8e+1)-1)/2) is EXACT for e<=8255: at triangular e,
    // 1+8e=(2r+1)^2 is an exact fp32 square (<=66049<2^24); between them the
    // margin >=0.015 >> 3e-5 fp error.
    {
        const float4* src4 = (const float4*)(net_out + (size_t)b * TRI);
        for (int q = t; q < TRI / 4; q += 256) {
            float4 f = src4[q];
            const int e = 4 * q;
            float vals[4] = {f.x, f.y, f.z, f.w};
            #pragma unroll
            for (int i = 0; i < 4; i++) {
                int ei = e + i;
                int r = (int)((sqrtf((float)(8 * ei) + 1.0f) - 1.0f) * 0.5f);
                int c = ei - ((r * (r + 1)) >> 1);
                Lsq[r * LDL + c] = (_Float16)vals[i];
            }
        }
    }
    __syncthreads();

    // ---- GEMM: M = L * L^T (16x16x32 f16 MFMA; wave w: bands w, w+4) ----
    {
        const int m = lane & 15;
        const int g = lane >> 4;
        f32x4 acc[2][8];
        #pragma unroll
        for (int bi = 0; bi < 2; bi++)
            #pragma unroll
            for (int j = 0; j < 8; j++) acc[bi][j] = (f32x4){0.f, 0.f, 0.f, 0.f};
        const int band0 = w, band1 = w + 4;
        #pragma unroll
        for (int kc = 0; kc < 4; kc++) {
            const int col = kc * 32 + g * 8;
            half8 a0 = *(const half8*)&Lsq[(16 * band0 + m) * LDL + col];
            half8 a1 = *(const half8*)&Lsq[(16 * band1 + m) * LDL + col];
            #pragma unroll
            for (int j = 0; j < 8; j++) {
                half8 bfr = *(const half8*)&Lsq[(16 * j + m) * LDL + col];
                acc[0][j] = __builtin_amdgcn_mfma_f32_16x16x32_f16(a0, bfr, acc[0][j], 0, 0, 0);
                acc[1][j] = __builtin_amdgcn_mfma_f32_16x16x32_f16(a1, bfr, acc[1][j], 0, 0, 0);
            }
        }
        __syncthreads();   // ALL Lsq reads complete before in-place overwrite

        #pragma unroll
        for (int bi = 0; bi < 2; bi++) {
            const int band = (bi == 0) ? band0 : band1;
            #pragma unroll
            for (int j = 0; j < 8; j++) {
                f32x4 a = acc[bi][j];
                half2v p01 = {(_Float16)a[0], (_Float16)a[1]};
                half2v p23 = {(_Float16)a[2], (_Float16)a[3]};
                uint2 pk;
                pk.x = __builtin_bit_cast(unsigned, p01);
                pk.y = __builtin_bit_cast(unsigned, p23);
                *(uint2*)&Lsq[(16 * j + m) * LDL + 16 * band + 4 * g] = pk;
            }
        }
    }
    __syncthreads();   // M ready in Lsq

    // ---- hoist this thread's half-row of M into registers (one time) ----
    const int r = t & 127, h = t >> 7;
    uint4 Mr[8];
    {
        const uint4* M4 = (const uint4*)&Lsq[r * LDL + 64 * h];
        #pragma unroll
        for (int c = 0; c < 8; c++) Mr[c] = M4[c];
    }

    // ---- wave-0 state init: x (2 elems/lane), gauge regs, first y ----
    float x0 = 0.f, x1 = 0.f, p0 = 0.f, p1 = 0.f, beta = 0.f;
    float u0c = 0.f, u1c = 0.f, u0m = 0.f, u1m = 0.f;
    const int l_ip = (lane + 8) & 63;                  // site (i+1, j)
    const int l_jp = (lane & 56) | ((lane + 1) & 7);   // site (i, j+1)
    const int l_im = (lane + 56) & 63;                 // site (i-1, j)
    const int l_jm = (lane & 56) | ((lane + 7) & 7);   // site (i, j-1)

    if (w == 0) {
        float s = vv.x * vv.x + vv.y * vv.y;
        #pragma unroll
        for (int o = 1; o < 64; o <<= 1) s += __shfl_xor(s, o, 64);
        float inv = 1.0f / sqrtf(s);
        x0 = vv.x * inv; x1 = vv.y * inv;
        u0c = uu.x; u1c = uu.y;
        u0m = __shfl(u0c, l_im, 64);   // u0 at (i-1, j)
        u1m = __shfl(u1c, l_jm, 64);   // u1 at (i, j-1)

        // first y = dd(x)
        float a0 = __shfl(x0, l_ip, 64), a1 = __shfl(x1, l_ip, 64);
        float b0 = __shfl(x0, l_jp, 64), b1 = __shfl(x1, l_jp, 64);
        float c0 = __shfl(x0, l_im, 64), c1 = __shfl(x1, l_im, 64);
        float d0 = __shfl(x0, l_jm, 64), d1 = __shfl(x1, l_jm, 64);
        float y0 = x0 - KAPPA * (u0c * a0 + u1c * b0 + u0m * c0 + u1m * d0);
        float y1 = x1 - KAPPA * (u0c * a1 + u1c * b1 + u0m * c1 + u1m * d1);
        half2v yp = {(_Float16)y0, (_Float16)y1};
        ys[lane] = __builtin_bit_cast(unsigned, yp);
    }
    __syncthreads();   // ys ready

    // =================== loop: 2 barriers per iteration ===================
    const uint4* Y4 = (const uint4*)&ys[32 * h];

    for (int it = 0; it < M_L; it++) {
        // ---- all threads: half-row matvec from registers, 4 accumulators ----
        {
            float aA = 0.f, aB = 0.f, aC = 0.f, aD = 0.f;
            #pragma unroll
            for (int c = 0; c < 8; c += 4) {
                uint4 y_0 = Y4[c],     y_1 = Y4[c + 1];
                uint4 y_2 = Y4[c + 2], y_3 = Y4[c + 3];
                aA = dot2h(Mr[c].x,     y_0.x, aA); aA = dot2h(Mr[c].y,     y_0.y, aA);
                aA = dot2h(Mr[c].z,     y_0.z, aA); aA = dot2h(Mr[c].w,     y_0.w, aA);
                aB = dot2h(Mr[c + 1].x, y_1.x, aB); aB = dot2h(Mr[c + 1].y, y_1.y, aB);
                aB = dot2h(Mr[c + 1].z, y_1.z, aB); aB = dot2h(Mr[c + 1].w, y_1.w, aB);
                aC = dot2h(Mr[c + 2].x, y_2.x, aC); aC = dot2h(Mr[c + 2].y, y_2.y, aC);
                aC = dot2h(Mr[c + 2].z, y_2.z, aC); aC = dot2h(Mr[c + 2].w, y_2.w, aC);
                aD = dot2h(Mr[c + 3].x, y_3.x, aD); aD = dot2h(Mr[c + 3].y, y_3.y, aD);
                aD = dot2h(Mr[c + 3].z, y_3.z, aD); aD = dot2h(Mr[c + 3].w, y_3.w, aD);
            }
            part[t] = (aA + aB) + (aC + aD);
        }
        __syncthreads();   // B1: part ready

        // ---- wave 0: combine, reduce, update, dd, broadcast y ----
        // R20: serial critical section -> elevated wave priority (T5/m191).
        if (w == 0) {
            __builtin_amdgcn_s_setprio(1);
            float2 pa = *(const float2*)&part[2 * lane];
            float2 pb = *(const float2*)&part[128 + 2 * lane];
            float z0 = pa.x + pb.x;     // z[2*lane]
            float z1 = pa.y + pb.y;     // z[2*lane+1]

            float s1 = z0 * x0 + z1 * x1;
            float s2 = z0 * z0 + z1 * z1;
            float s3 = z0 * p0 + z1 * p1;
            #pragma unroll
            for (int o = 1; o < 64; o <<= 1) {
                s1 += __shfl_xor(s1, o, 64);
                s2 += __shfl_xor(s2, o, 64);
                s3 += __shfl_xor(s3, o, 64);
            }
            float alpha = s1;
            float b2 = s2 - alpha * alpha - beta * (2.0f * s3 - beta);
            float bn = sqrtf(fmaxf(b2, 0.0f));
            float w0 = z0 - alpha * x0 - beta * p0;
            float w1 = z1 - alpha * x1 - beta * p1;
            float inv = 1.0f / (bn + 1e-30f);
            p0 = x0; p1 = x1;
            x0 = w0 * inv; x1 = w1 * inv;
            beta = bn;
            if (lane == 0) {
                ab_s[it]      = alpha;   // LDS scratch, no global round-trip
                ab_s[10 + it] = bn;
            }

            // dd for next iteration
            float a0 = __shfl(x0, l_ip, 64), a1 = __shfl(x1, l_ip, 64);
            float b0 = __shfl(x0, l_jp, 64), b1 = __shfl(x1, l_jp, 64);
            float c0 = __shfl(x0, l_im, 64), c1 = __shfl(x1, l_im, 64);
            float d0 = __shfl(x0, l_jm, 64), d1 = __shfl(x1, l_jm, 64);
            float y0 = x0 - KAPPA * (u0c * a0 + u1c * b0 + u0m * c0 + u1m * d0);
            float y1 = x1 - KAPPA * (u0c * a1 + u1c * b1 + u0m * c1 + u1m * d1);
            half2v yp = {(_Float16)y0, (_Float16)y1};
            ys[lane] = __builtin_bit_cast(unsigned, yp);
            __builtin_amdgcn_s_setprio(0);
        }
        __syncthreads();   // B2: ys ready for next matvec; also makes ab_s
                           //     visible to ALL waves after the last iter
    }

    // ============ eig tail: ONE wave (b&3), lane-split Sturm ============
    if (w != (b & 3)) return;   // no barriers below this point
    __builtin_amdgcn_s_setprio(1);   // R20: serial fp64 chain, block holds LDS

    double a[M_L], off2[M_L - 1], offa[M_L - 1];
    #pragma unroll
    for (int i = 0; i < M_L; i++) a[i] = (double)ab_s[i];
    #pragma unroll
    for (int i = 0; i < M_L - 1; i++) {
        double bb = (double)ab_s[10 + i];
        offa[i] = fabs(bb);
        off2[i] = bb * bb;
    }
    double glo = 1e300, ghi = -1e300;
    #pragma unroll
    for (int i = 0; i < M_L; i++) {
        double rr = 0.0;
        if (i > 0) rr += offa[i - 1];
        if (i < M_L - 1) rr += offa[i];
        glo = fmin(glo, a[i] - rr);
        ghi = fmax(ghi, a[i] + rr);
    }

    const int kk = lane & 31;
    const bool topHalf = (lane >= 32);

    // Phase 1: lanes 0-31 find lmax (K=10), lanes 32-63 find lmin (K=1);
    // 33-section x 4 rounds; branchless bracket update (p=32 = "none").
    const int K = topHalf ? 1 : M_L;
    double lo = glo, hi = ghi;
    for (int round = 0; round < 4; round++) {
        double wdt = (hi - lo) * (1.0 / 33.0);
        double x = lo + wdt * (double)(kk + 1);
        int cnt = sturm_count10(a, off2, x);
        unsigned long long m64 = __ballot(cnt >= K);
        unsigned mm = topHalf ? (unsigned)(m64 >> 32)
                              : (unsigned)(m64 & 0xffffffffu);
        int p = (mm == 0u) ? 32 : (__ffs(mm) - 1);
        double nlo = lo + wdt * (double)p;
        hi = (mm == 0u) ? hi : (lo + wdt * (double)(p + 1));
        lo = nlo;
    }
    double mid = 0.5 * (lo + hi);
    double lmax = __shfl(mid, 0, 64);
    double lmin = __shfl(mid, 32, 64);
    double maxabs = fmax(fabs(lmax), fabs(lmin));

    // Phase 2: window |lambda|min -- lanes 0-31 eval +s, lanes 32-63 eval -s
    // at mirrored s; combine via shfl_xor(32); 33-section x 4 rounds.
    double wlo = 0.0, whi = maxabs;
    for (int round = 0; round < 4; round++) {
        double wdt = (whi - wlo) * (1.0 / 33.0);
        double s = wlo + wdt * (double)(kk + 1);
        double x = topHalf ? -s : s;
        int cnt = sturm_count10(a, off2, x);
        int o = __shfl_xor(cnt, 32, 64);
        int inwin = topHalf ? (o - cnt) : (cnt - o);
        unsigned long long m64 = __ballot(inwin >= 1);
        unsigned mm = (unsigned)(m64 & 0xffffffffu);   // halves mirror
        int p = (mm == 0u) ? 32 : (__ffs(mm) - 1);
        double nlo = wlo + wdt * (double)p;
        whi = (mm == 0u) ? whi : (wlo + wdt * (double)(p + 1));
        wlo = nlo;
    }
    double minabs = 0.5 * (wlo + whi);
    __builtin_amdgcn_s_setprio(0);
    if (lane == 0) contrib[b] = (float)(maxabs * maxabs - minabs * minabs);
}

// ---------------------------------------------------------------------------
// Kernel 2: reduce 2048 contributions -> d_out[0] (mean)
// ---------------------------------------------------------------------------
__global__ __launch_bounds__(1024) void reduce_kernel(
    const float* __restrict__ contrib, float* __restrict__ out)
{
    __shared__ float red[16];
    int t = threadIdx.x;
    float s = contrib[t] + contrib[t + 1024];
    #pragma unroll
    for (int o = 32; o > 0; o >>= 1) s += __shfl_down(s, o, 64);
    if ((t & 63) == 0) red[t >> 6] = s;
    __syncthreads();
    if (t < 64) {
        float r = (t < 16) ? red[t] : 0.0f;
        #pragma unroll
        for (int o = 8; o > 0; o >>= 1) r += __shfl_down(r, o, 64);
        if (t == 0) out[0] = r / (float)BATCH;
    }
}

extern "C" void kernel_launch(void* const* d_in, const int* in_sizes, int n_in,
                              void* d_out, int out_size, void* d_ws, size_t ws_size,
                              hipStream_t stream) {
    const float* net_out = (const float*)d_in[0];
    const float* U1      = (const float*)d_in[1];
    const float* v       = (const float*)d_in[2];
    float* contrib = (float*)d_ws;   // BATCH floats

    lanczos_kernel<<<BATCH, 256, 0, stream>>>(net_out, U1, v, contrib);
    reduce_kernel<<<1, 1024, 0, stream>>>(contrib, (float*)d_out);
}